// Round 10
// baseline (2106.538 us; speedup 1.0000x reference)
//
#include <hip/hip_runtime.h>
#include <stdint.h>

#define BETA 0.9f

typedef unsigned short u16;
typedef unsigned char u8;
typedef _Float16 f16x8 __attribute__((ext_vector_type(8)));
typedef float f32x4 __attribute__((ext_vector_type(4)));

// async global->LDS, 16B per lane; lds ptr is wave-uniform base (+lane*16 by HW)
__device__ __forceinline__ void async_copy16(const void* g, void* l) {
  __builtin_amdgcn_global_load_lds(
      (const __attribute__((address_space(1))) uint32_t*)g,
      (__attribute__((address_space(3))) uint32_t*)l, 16, 0, 0);
}

// byte (8 spike bits) -> 8 f16 (bit * 2^-11, f16 bits 0x1000) as uint4
__device__ __forceinline__ uint4 expandB4(uint32_t byte) {
  uint32_t z = byte | (byte << 15);  // bit 2m at 2m, bit 2m+1 at 2m+16
  uint4 r;
  r.x = ((z >> 0) & 0x10001u) << 12;
  r.y = ((z >> 2) & 0x10001u) << 12;
  r.z = ((z >> 4) & 0x10001u) << 12;
  r.w = ((z >> 6) & 0x10001u) << 12;
  return r;
}

// ---------------------------------------------------------------------------
// prep: fp16 2-split with scale folded into A (B always contributes 2^-11):
//   hi-part stores f16(f16(w)*2048)   [exact: power-of-2 shift]
//   mid-part stores f16((w-f16(w))*2048)
// Layout A[virt][ct][tap][co64][ci32]; 12KB DMA units; granule XOR-swizzle
// (g ^ ((co>>1)&3)) keeps LDS b128 A-reads conflict-free. Also fc transposes.
// ---------------------------------------------------------------------------
__global__ void prep_kernel(const float* __restrict__ W2, const float* __restrict__ W3,
                            const float* __restrict__ fw1, const float* __restrict__ fw2,
                            u16* __restrict__ A2c, u16* __restrict__ A3c,
                            float* __restrict__ fw1T, float* __restrict__ fw2T) {
  int o = blockIdx.x * 256 + threadIdx.x;
  if (o < 98304) {  // W2: (tap, co, ci), 3*128*256
    int tap = o >> 15, r = o & 32767, co = r >> 8, ci = r & 255;
    float w = W2[(co * 256 + ci) * 3 + tap];
    float h = (float)(_Float16)w;
    _Float16 hv = (_Float16)(h * 2048.0f);
    _Float16 mv = (_Float16)((w - h) * 2048.0f);
    u16 hb, mb;
    __builtin_memcpy(&hb, &hv, 2);
    __builtin_memcpy(&mb, &mv, 2);
    int c = ci >> 5, cl = ci & 31;
    int ct = co >> 6, col = co & 63;
    int g = ((cl >> 3) ^ ((co >> 1) & 3)) & 3;       // swizzled granule
    int pos = g * 8 + (cl & 7);
    A2c[((((c * 2 + 0) * 2 + ct) * 3 + tap) * 64 + col) * 32 + pos] = hb;
    A2c[((((c * 2 + 1) * 2 + ct) * 3 + tap) * 64 + col) * 32 + pos] = mb;
  }
  int o2 = o - 98304;  // W3: (tap, co, ci), 3*64*128 (NCT=1)
  if (o2 >= 0 && o2 < 24576) {
    int tap = o2 >> 13, r = o2 & 8191, co = r >> 7, ci = r & 127;
    float w = W3[(co * 128 + ci) * 3 + tap];
    float h = (float)(_Float16)w;
    _Float16 hv = (_Float16)(h * 2048.0f);
    _Float16 mv = (_Float16)((w - h) * 2048.0f);
    u16 hb, mb;
    __builtin_memcpy(&hb, &hv, 2);
    __builtin_memcpy(&mb, &mv, 2);
    int c = ci >> 5, cl = ci & 31;
    int g = ((cl >> 3) ^ ((co >> 1) & 3)) & 3;
    int pos = g * 8 + (cl & 7);
    A3c[(((c * 2 + 0) * 3 + tap) * 64 + co) * 32 + pos] = hb;
    A3c[(((c * 2 + 1) * 3 + tap) * 64 + co) * 32 + pos] = mb;
  }
  int o3 = o - (98304 + 24576);
  if (o3 >= 0 && o3 < 25600) {
    int f = o3 / 100, i = o3 % 100;
    fw1T[o3] = fw1[i * 256 + f];
  }
  int o4 = o - (98304 + 24576 + 25600);
  if (o4 >= 0 && o4 < 4000) {
    int i = o4 / 40, j = o4 % 40;
    fw2T[o4] = fw2[j * 100 + i];
  }
}

// ---------------------------------------------------------------------------
// conv1 (2->256, K=5, pad=2) + LIF1; writes byte-transposed spikes
// SBT2[b][l][g][t] (byte = spikes of co in [8g,8g+8), bit j = co 8g+j).
// ---------------------------------------------------------------------------
__global__ __launch_bounds__(256) void conv1_lif_kernel(
    const float* __restrict__ x, const float* __restrict__ W1,
    const float* __restrict__ b1, u8* __restrict__ SBT2) {
  __shared__ float xl[2][132];
  __shared__ u16 bl[8][128];
  int b = blockIdx.x, g = blockIdx.y;
  int tid = threadIdx.x;
  for (int i = tid; i < 264; i += 256) {
    int ci = i / 132, idx = i % 132, lg = idx - 2;
    xl[ci][idx] = (lg >= 0 && lg < 128) ? x[(b * 2 + ci) * 128 + lg] : 0.0f;
  }
  __syncthreads();
  int cosub = tid >> 5, tx = tid & 31;
  int co = g * 8 + cosub;
  float w[2][5];
#pragma unroll
  for (int ci = 0; ci < 2; ++ci)
#pragma unroll
    for (int k = 0; k < 5; ++k) w[ci][k] = W1[(co * 2 + ci) * 5 + k];
  float bias = b1[co];
  float cur[4];
#pragma unroll
  for (int j = 0; j < 4; ++j) {
    float acc = bias;
#pragma unroll
    for (int ci = 0; ci < 2; ++ci)
#pragma unroll
      for (int k = 0; k < 5; ++k) acc += w[ci][k] * xl[ci][4 * tx + j + k];
    cur[j] = acc;
  }
  float m[4] = {0.f, 0.f, 0.f, 0.f}, sp[4] = {0.f, 0.f, 0.f, 0.f};
  uint32_t bits[4] = {0u, 0u, 0u, 0u};
#pragma unroll
  for (int t = 0; t < 16; ++t) {
#pragma unroll
    for (int j = 0; j < 4; ++j) {
      m[j] = BETA * m[j] + cur[j] - sp[j];
      bool s = m[j] > 1.0f;
      bits[j] |= ((uint32_t)s) << t;
      sp[j] = s ? 1.0f : 0.0f;
    }
  }
#pragma unroll
  for (int j = 0; j < 4; ++j) bl[cosub][4 * tx + j] = (u16)bits[j];
  __syncthreads();
  if (tid < 128) {
    int l = tid;
    uint32_t wv[8];
#pragma unroll
    for (int j = 0; j < 8; ++j) wv[j] = bl[j][l];
    uint32_t ov[4];
#pragma unroll
    for (int k = 0; k < 4; ++k) {
      uint32_t v = 0;
#pragma unroll
      for (int tt = 0; tt < 4; ++tt) {
        int t = k * 4 + tt;
        uint32_t by = 0;
#pragma unroll
        for (int j = 0; j < 8; ++j) by |= ((wv[j] >> t) & 1u) << j;
        v |= by << (8 * tt);
      }
      ov[k] = v;
    }
    *(uint4*)(SBT2 + ((size_t)(b * 128 + l) * 32 + g) * 16) =
        make_uint4(ov[0], ov[1], ov[2], ov[3]);
  }
}

// ---------------------------------------------------------------------------
// MFMA conv (CIN->COUT, K=3, pad=1) + LIF.  [r9 + shared B expansion in LDS]
// Block tile: 64 co (z) x 16 l (y); waves 2x2 (wy: 32-co, wx: 8-l); NT=8.
// A: async double-buffered LDS (12KB), one barrier per part.
// B: per phys chunk, 256 threads expand 1152 spike bytes into LDS
//    [18 row][16 t][32 ci] f16 (granule swizz g^(t&3)); staging u32s are
//    register-prefetched one chunk ahead; lanes read Bf via 10 ds_read_b128
//    once per chunk (regs reused across both parts). No per-lane expansion.
// ---------------------------------------------------------------------------
template <int CIN, int COUT, bool SBTOUT>
__global__ __launch_bounds__(256, 3) void conv_mfma_kernel(
    const u8* __restrict__ SBT, const u16* __restrict__ Agc,
    const float* __restrict__ bias, void* __restrict__ outp) {
  constexpr int NPHYS = CIN / 32;
  constexpr int NVIRT = 2 * NPHYS;
  constexpr int NCT = COUT / 64;
  constexpr int MT = 2;                    // 16-co tiles per wave
  constexpr int NT = 8;                    // l-positions per wave
  constexpr int GB = CIN / 8;
  constexpr int ABYTES = 3 * 64 * 32 * 2;  // 12288 per (virt,ct) A block
  constexpr int AW = ABYTES / 4;
  constexpr int AISS = AW / 1024;          // 3
  __shared__ __align__(16) char lds[2 * ABYTES];   // A dbuf; epilogue reuses
  __shared__ __align__(16) u16 Bs[18 * 16 * 32];   // 18432 B expanded B tile

  int b = blockIdx.x, lb = blockIdx.y * 16, ct = blockIdx.z;
  int tid = threadIdx.x, lane = tid & 63, wid = tid >> 6;
  int wx = wid & 1, wy = wid >> 1;
  int q = lane >> 4, xx = lane & 15;
  int mloc = wy * 32;                      // co_local base for this wave
  int qs8 = (q ^ ((xx >> 1) & 3)) * 8;     // A swizzled granule offset (u16)
  int bswz = (q ^ (xx & 3)) * 8;           // B swizzled granule offset (u16)

  f32x4 acc[MT][NT];
#pragma unroll
  for (int mt = 0; mt < MT; ++mt)
#pragma unroll
    for (int nt = 0; nt < NT; ++nt) acc[mt][nt] = (f32x4){0.f, 0.f, 0.f, 0.f};

  // staging-task helpers: task s in [0,288): row=s>>4, g=(s>>2)&3, tq=s&3
  auto stage_load = [&](int pn, int s) -> uint32_t {
    int row = s >> 4, g = (s >> 2) & 3, tq = s & 3;
    int l_in = lb + row - 1;
    if ((unsigned)l_in >= 128u) return 0u;
    return *(const uint32_t*)(SBT + ((size_t)(b * 128 + l_in) * GB + pn * 4 + g) * 16 + tq * 4);
  };
  auto stage_write = [&](int s, uint32_t w4) {
    int row = s >> 4, g = (s >> 2) & 3, tq = s & 3;
#pragma unroll
    for (int i = 0; i < 4; ++i) {
      uint32_t by = (w4 >> (8 * i)) & 0xFFu;
      int t = tq * 4 + i;
      int gs = g ^ i;  // t&3 == i
      *(uint4*)(Bs + (row * 16 + t) * 32 + gs * 8) = expandB4(by);
    }
  };

  // prologue: prefetch staging regs for chunk 0; issue A-DMA for v=0
  uint32_t w4a = stage_load(0, tid);
  uint32_t w4b = (tid < 32) ? stage_load(0, tid + 256) : 0u;
  {
    const char* gsrc = (const char*)Agc + (size_t)ct * ABYTES +
                       (size_t)wid * AW + lane * 16;
    char* ldst = lds + wid * AW;
#pragma unroll
    for (int i = 0; i < AISS; ++i) async_copy16(gsrc + i * 1024, ldst + i * 1024);
  }

  f16x8 Bf[10];
#pragma unroll 2
  for (int v = 0; v < NVIRT; ++v) {
    __syncthreads();  // drains A-DMA(v); separates Bs readers/writers
    if ((v & 1) == 0) {
      stage_write(tid, w4a);
      if (tid < 32) stage_write(tid + 256, w4b);
      __syncthreads();  // Bs visible to all waves
    }
    if (v + 1 < NVIRT) {  // issue A-DMA(v+1) (drained at next top barrier)
      const char* gsrc = (const char*)Agc + ((size_t)(v + 1) * NCT + ct) * ABYTES +
                         (size_t)wid * AW + lane * 16;
      char* ldst = lds + ((v + 1) & 1) * ABYTES + wid * AW;
#pragma unroll
      for (int i = 0; i < AISS; ++i) async_copy16(gsrc + i * 1024, ldst + i * 1024);
    }
    if ((v & 1) == 0) {
      int pn = (v >> 1) + 1;
      if (pn < NPHYS) {  // prefetch next chunk's staging u32s into regs
        w4a = stage_load(pn, tid);
        if (tid < 32) w4b = stage_load(pn, tid + 256);
      }
      // read this chunk's B fragments once; regs reused across both parts
#pragma unroll
      for (int u = 0; u < 10; ++u)
        Bf[u] = *(const f16x8*)(Bs + ((wx * 8 + u) * 16 + xx) * 32 + bswz);
    }
    const u16* Asv = (const u16*)(lds + (v & 1) * ABYTES);
#pragma unroll
    for (int tap = 0; tap < 3; ++tap)
#pragma unroll
      for (int mt = 0; mt < MT; ++mt) {
        f16x8 Af = *(const f16x8*)(Asv + ((size_t)(tap * 64 + mloc + mt * 16 + xx)) * 32 + qs8);
#pragma unroll
        for (int nt = 0; nt < NT; ++nt)
          acc[mt][nt] = __builtin_amdgcn_mfma_f32_16x16x32_f16(
              Af, Bf[nt + tap], acc[mt][nt], 0, 0, 0);
      }
  }
  __syncthreads();

  // epilogue: per-wave scr transpose (stride 19, <=2-way), 2 passes per mt
  float* scr = (float*)(void*)lds + wid * 1216;  // 64 rows x 19 words
  u16* bl = (u16*)(lds + 19456);                 // [64 co_local][16 l_local]
#pragma unroll
  for (int mt = 0; mt < MT; ++mt) {
#pragma unroll
    for (int h = 0; h < 2; ++h) {
#pragma unroll
      for (int u2 = 0; u2 < 4; ++u2)
#pragma unroll
        for (int r = 0; r < 4; ++r)
          scr[(u2 * 16 + q * 4 + r) * 19 + xx] = acc[mt][h * 4 + u2][r];
      __syncthreads();
      int col = mloc + mt * 16 + xx;
      float bc = bias[ct * 64 + col];
      const float* rowp = scr + (q * 16 + xx) * 19;
      float mm = 0.f, sp = 0.f;
      uint32_t bits = 0;
#pragma unroll
      for (int t = 0; t < 16; ++t) {
        float cur = rowp[t] + bc;
        mm = BETA * mm + cur - sp;
        bool s = mm > 1.0f;
        bits |= ((uint32_t)s) << t;
        sp = s ? 1.0f : 0.0f;
      }
      bl[col * 16 + wx * 8 + h * 4 + q] = (u16)bits;
      __syncthreads();
    }
  }

  if constexpr (SBTOUT) {
    constexpr int GBo = COUT / 8;   // full-row granule count
    if (tid < 128) {                // 8 g_local x 16 l
      int g = tid & 7, ll = tid >> 3;
      uint32_t wv[8];
#pragma unroll
      for (int j = 0; j < 8; ++j) wv[j] = bl[(8 * g + j) * 16 + ll];
      uint32_t ov[4];
#pragma unroll
      for (int k = 0; k < 4; ++k) {
        uint32_t v = 0;
#pragma unroll
        for (int tt = 0; tt < 4; ++tt) {
          int t = k * 4 + tt;
          uint32_t by = 0;
#pragma unroll
          for (int j = 0; j < 8; ++j) by |= ((wv[j] >> t) & 1u) << j;
          v |= by << (8 * tt);
        }
        ov[k] = v;
      }
      *(uint4*)((u8*)outp + ((size_t)(b * 128 + lb + ll) * GBo + ct * 8 + g) * 16) =
          make_uint4(ov[0], ov[1], ov[2], ov[3]);
    }
  } else {
    if (tid < 128) {  // 64 co x 2 halves of 8 l (16B each)
      int col = tid >> 1, hf = tid & 1;
      uint4 v = *(const uint4*)(bl + col * 16 + hf * 8);
      *(uint4*)((u16*)outp + ((size_t)b * COUT + ct * 64 + col) * 128 + lb + hf * 8) = v;
    }
  }
}

// ---------------------------------------------------------------------------
// head: conv4 (64->2) + LIF4, fc1 (256->100) + LIF5, fc2 accumulated (popcount)
// ---------------------------------------------------------------------------
__global__ __launch_bounds__(256) void head_kernel(
    const u16* __restrict__ s3bits, const float* __restrict__ W4,
    const float* __restrict__ b4, const float* __restrict__ fw1T,
    const float* __restrict__ fb1, const float* __restrict__ fw2T,
    const float* __restrict__ fb2, float* __restrict__ out) {
  __shared__ u16 s3l[64][130];
  __shared__ float W4l[384];
  __shared__ u16 flat4[256];
  __shared__ u16 s5b[100];
  int b = blockIdx.x, tid = threadIdx.x;

  for (int i = tid; i < 64 * 130; i += 256) {
    int ci = i / 130, idx = i % 130, lg = idx - 1;
    s3l[ci][idx] = (lg >= 0 && lg < 128) ? s3bits[((size_t)b * 64 + ci) * 128 + lg] : (u16)0;
  }
  for (int i = tid; i < 384; i += 256) W4l[i] = W4[i];
  __syncthreads();

  {
    int co = tid >> 7, l = tid & 127;
    float acc4[16];
#pragma unroll
    for (int t = 0; t < 16; ++t) acc4[t] = 0.f;
    for (int ci = 0; ci < 64; ++ci) {
#pragma unroll
      for (int k = 0; k < 3; ++k) {
        float wv = W4l[(co * 64 + ci) * 3 + k];
        uint32_t msk = s3l[ci][l + k];
#pragma unroll
        for (int t = 0; t < 16; ++t)
          acc4[t] = fmaf(wv, (float)((msk >> t) & 1u), acc4[t]);
      }
    }
    float bc = b4[co];
    float m = 0.f, sp = 0.f;
    uint32_t bits = 0;
#pragma unroll
    for (int t = 0; t < 16; ++t) {
      m = BETA * m + (acc4[t] + bc) - sp;
      bool s = m > 1.0f;
      bits |= ((uint32_t)s) << t;
      sp = s ? 1.0f : 0.0f;
    }
    flat4[tid] = (u16)bits;
  }
  __syncthreads();

  if (tid < 100) {
    float acc5[16];
#pragma unroll
    for (int t = 0; t < 16; ++t) acc5[t] = 0.f;
    for (int f = 0; f < 256; ++f) {
      float wv = fw1T[f * 100 + tid];
      uint32_t msk = flat4[f];
#pragma unroll
      for (int t = 0; t < 16; ++t)
        acc5[t] = fmaf(wv, (float)((msk >> t) & 1u), acc5[t]);
    }
    float bc = fb1[tid];
    float m = 0.f, sp = 0.f;
    uint32_t bits = 0;
#pragma unroll
    for (int t = 0; t < 16; ++t) {
      m = BETA * m + (acc5[t] + bc) - sp;
      bool s = m > 1.0f;
      bits |= ((uint32_t)s) << t;
      sp = s ? 1.0f : 0.0f;
    }
    s5b[tid] = (u16)bits;
  }
  __syncthreads();

  if (tid < 40) {
    float a = 0.f;
    for (int i = 0; i < 100; ++i) {
      float wv = fw2T[i * 40 + tid];
      a = fmaf(wv, (float)__popc((uint32_t)s5b[i]), a);
    }
    out[b * 40 + tid] = a * 0.0625f + fb2[tid];
  }
}

// ---------------------------------------------------------------------------
extern "C" void kernel_launch(void* const* d_in, const int* in_sizes, int n_in,
                              void* d_out, int out_size, void* d_ws, size_t ws_size,
                              hipStream_t stream) {
  const float* x   = (const float*)d_in[0];
  const float* W1  = (const float*)d_in[1];
  const float* b1  = (const float*)d_in[2];
  const float* W2  = (const float*)d_in[3];
  const float* b2  = (const float*)d_in[4];
  const float* W3  = (const float*)d_in[5];
  const float* b3  = (const float*)d_in[6];
  const float* W4  = (const float*)d_in[7];
  const float* b4  = (const float*)d_in[8];
  const float* fw1 = (const float*)d_in[9];
  const float* fb1 = (const float*)d_in[10];
  const float* fw2 = (const float*)d_in[11];
  const float* fb2 = (const float*)d_in[12];
  float* out = (float*)d_out;

  char* ws = (char*)d_ws;
  u16*   A2c  = (u16*)(ws);                       // 393216 B [virt][ct][tap][co64][ci32]
  u16*   A3c  = (u16*)(ws + 393216);              //  98304 B
  float* fw1T = (float*)(ws + 491520);            // 102400 B
  float* fw2T = (float*)(ws + 593920);            //  16000 B (pad to 610304)
  u8*    SBT2 = (u8*)(ws + 610304);               // 134217728 B [b][l][32][16]
  u8*    SBT3 = (u8*)(ws + 610304 + 134217728);   //  67108864 B [b][l][16][16]
  u16*   s3b  = (u16*)(ws + 610304 + 134217728 + 67108864);  // 33554432 B u16 [b][co][l]
  // total: 235,491,328 B

  prep_kernel<<<dim3(596), dim3(256), 0, stream>>>(W2, W3, fw1, fw2, A2c, A3c, fw1T, fw2T);
  conv1_lif_kernel<<<dim3(2048, 32), dim3(256), 0, stream>>>(x, W1, b1, SBT2);
  conv_mfma_kernel<256, 128, true><<<dim3(2048, 8, 2), dim3(256), 0, stream>>>(SBT2, A2c, b2, SBT3);
  conv_mfma_kernel<128, 64, false><<<dim3(2048, 8, 1), dim3(256), 0, stream>>>(SBT3, A3c, b3, s3b);
  head_kernel<<<dim3(2048), dim3(256), 0, stream>>>(s3b, W4, b4, fw1T, fb1, fw2T, fb2, out);
}

// Round 11
// 2043.876 us; speedup vs baseline: 1.0307x; 1.0307x over previous
//
#include <hip/hip_runtime.h>
#include <stdint.h>

#define BETA 0.9f

typedef unsigned short u16;
typedef unsigned char u8;
typedef _Float16 f16x8 __attribute__((ext_vector_type(8)));
typedef float f32x4 __attribute__((ext_vector_type(4)));

// async global->LDS, 16B per lane; lds ptr is wave-uniform base (+lane*16 by HW)
__device__ __forceinline__ void async_copy16(const void* g, void* l) {
  __builtin_amdgcn_global_load_lds(
      (const __attribute__((address_space(1))) uint32_t*)g,
      (__attribute__((address_space(3))) uint32_t*)l, 16, 0, 0);
}

// byte (8 spike bits) -> 8 f16 (bit * 2^-11, f16 bits 0x1000) as uint4
__device__ __forceinline__ uint4 expandB4(uint32_t byte) {
  uint32_t z = byte | (byte << 15);  // bit 2m at 2m, bit 2m+1 at 2m+16
  uint4 r;
  r.x = ((z >> 0) & 0x10001u) << 12;
  r.y = ((z >> 2) & 0x10001u) << 12;
  r.z = ((z >> 4) & 0x10001u) << 12;
  r.w = ((z >> 6) & 0x10001u) << 12;
  return r;
}

// ---------------------------------------------------------------------------
// prep: fp16 2-split with scale folded into A (B always contributes 2^-11):
//   hi-part stores f16(f16(w)*2048)   [exact: power-of-2 shift]
//   mid-part stores f16((w-f16(w))*2048)
// Layout A[virt][ct][tap][co64][ci32]; 12KB DMA units; granule XOR-swizzle
// (g ^ ((co>>1)&3)) keeps LDS b128 A-reads conflict-free. Also fc transposes.
// ---------------------------------------------------------------------------
__global__ void prep_kernel(const float* __restrict__ W2, const float* __restrict__ W3,
                            const float* __restrict__ fw1, const float* __restrict__ fw2,
                            u16* __restrict__ A2c, u16* __restrict__ A3c,
                            float* __restrict__ fw1T, float* __restrict__ fw2T) {
  int o = blockIdx.x * 256 + threadIdx.x;
  if (o < 98304) {  // W2: (tap, co, ci), 3*128*256
    int tap = o >> 15, r = o & 32767, co = r >> 8, ci = r & 255;
    float w = W2[(co * 256 + ci) * 3 + tap];
    float h = (float)(_Float16)w;
    _Float16 hv = (_Float16)(h * 2048.0f);
    _Float16 mv = (_Float16)((w - h) * 2048.0f);
    u16 hb, mb;
    __builtin_memcpy(&hb, &hv, 2);
    __builtin_memcpy(&mb, &mv, 2);
    int c = ci >> 5, cl = ci & 31;
    int ct = co >> 6, col = co & 63;
    int g = ((cl >> 3) ^ ((co >> 1) & 3)) & 3;       // swizzled granule
    int pos = g * 8 + (cl & 7);
    A2c[((((c * 2 + 0) * 2 + ct) * 3 + tap) * 64 + col) * 32 + pos] = hb;
    A2c[((((c * 2 + 1) * 2 + ct) * 3 + tap) * 64 + col) * 32 + pos] = mb;
  }
  int o2 = o - 98304;  // W3: (tap, co, ci), 3*64*128 (NCT=1)
  if (o2 >= 0 && o2 < 24576) {
    int tap = o2 >> 13, r = o2 & 8191, co = r >> 7, ci = r & 127;
    float w = W3[(co * 128 + ci) * 3 + tap];
    float h = (float)(_Float16)w;
    _Float16 hv = (_Float16)(h * 2048.0f);
    _Float16 mv = (_Float16)((w - h) * 2048.0f);
    u16 hb, mb;
    __builtin_memcpy(&hb, &hv, 2);
    __builtin_memcpy(&mb, &mv, 2);
    int c = ci >> 5, cl = ci & 31;
    int g = ((cl >> 3) ^ ((co >> 1) & 3)) & 3;
    int pos = g * 8 + (cl & 7);
    A3c[(((c * 2 + 0) * 3 + tap) * 64 + co) * 32 + pos] = hb;
    A3c[(((c * 2 + 1) * 3 + tap) * 64 + co) * 32 + pos] = mb;
  }
  int o3 = o - (98304 + 24576);
  if (o3 >= 0 && o3 < 25600) {
    int f = o3 / 100, i = o3 % 100;
    fw1T[o3] = fw1[i * 256 + f];
  }
  int o4 = o - (98304 + 24576 + 25600);
  if (o4 >= 0 && o4 < 4000) {
    int i = o4 / 40, j = o4 % 40;
    fw2T[o4] = fw2[j * 100 + i];
  }
}

// ---------------------------------------------------------------------------
// conv1 (2->256, K=5, pad=2) + LIF1; writes byte-transposed spikes
// SBT2[b][l][g][t] (byte = spikes of co in [8g,8g+8), bit j = co 8g+j).
// ---------------------------------------------------------------------------
__global__ __launch_bounds__(256) void conv1_lif_kernel(
    const float* __restrict__ x, const float* __restrict__ W1,
    const float* __restrict__ b1, u8* __restrict__ SBT2) {
  __shared__ float xl[2][132];
  __shared__ u16 bl[8][128];
  int b = blockIdx.x, g = blockIdx.y;
  int tid = threadIdx.x;
  for (int i = tid; i < 264; i += 256) {
    int ci = i / 132, idx = i % 132, lg = idx - 2;
    xl[ci][idx] = (lg >= 0 && lg < 128) ? x[(b * 2 + ci) * 128 + lg] : 0.0f;
  }
  __syncthreads();
  int cosub = tid >> 5, tx = tid & 31;
  int co = g * 8 + cosub;
  float w[2][5];
#pragma unroll
  for (int ci = 0; ci < 2; ++ci)
#pragma unroll
    for (int k = 0; k < 5; ++k) w[ci][k] = W1[(co * 2 + ci) * 5 + k];
  float bias = b1[co];
  float cur[4];
#pragma unroll
  for (int j = 0; j < 4; ++j) {
    float acc = bias;
#pragma unroll
    for (int ci = 0; ci < 2; ++ci)
#pragma unroll
      for (int k = 0; k < 5; ++k) acc += w[ci][k] * xl[ci][4 * tx + j + k];
    cur[j] = acc;
  }
  float m[4] = {0.f, 0.f, 0.f, 0.f}, sp[4] = {0.f, 0.f, 0.f, 0.f};
  uint32_t bits[4] = {0u, 0u, 0u, 0u};
#pragma unroll
  for (int t = 0; t < 16; ++t) {
#pragma unroll
    for (int j = 0; j < 4; ++j) {
      m[j] = BETA * m[j] + cur[j] - sp[j];
      bool s = m[j] > 1.0f;
      bits[j] |= ((uint32_t)s) << t;
      sp[j] = s ? 1.0f : 0.0f;
    }
  }
#pragma unroll
  for (int j = 0; j < 4; ++j) bl[cosub][4 * tx + j] = (u16)bits[j];
  __syncthreads();
  if (tid < 128) {
    int l = tid;
    uint32_t wv[8];
#pragma unroll
    for (int j = 0; j < 8; ++j) wv[j] = bl[j][l];
    uint32_t ov[4];
#pragma unroll
    for (int k = 0; k < 4; ++k) {
      uint32_t v = 0;
#pragma unroll
      for (int tt = 0; tt < 4; ++tt) {
        int t = k * 4 + tt;
        uint32_t by = 0;
#pragma unroll
        for (int j = 0; j < 8; ++j) by |= ((wv[j] >> t) & 1u) << j;
        v |= by << (8 * tt);
      }
      ov[k] = v;
    }
    *(uint4*)(SBT2 + ((size_t)(b * 128 + l) * 32 + g) * 16) =
        make_uint4(ov[0], ov[1], ov[2], ov[3]);
  }
}

// ---------------------------------------------------------------------------
// MFMA conv (CIN->COUT, K=3, pad=1) + LIF.  [r10 + PADDED B tile, no swizzle]
// Block tile: 64 co (z) x 16 l (y); waves 2x2 (wy: 32-co, wx: 8-l); NT=8.
// A: async double-buffered LDS (12KB), one barrier per part; r7 XOR-swizzle.
// B: per phys chunk, 256 threads expand 1152 spike bytes into LDS tile
//    Bs[(row*16+t)][40 u16] (stride 80B: writes spread as (tq*16+g*4+20i),
//    reads as (xx*20+q*4) -> both uniform over banks, conflict-free);
//    staging u32s register-prefetched one chunk ahead; lanes read Bf via
//    10 ds_read_b128 once per chunk, regs reused across both split parts.
// ---------------------------------------------------------------------------
template <int CIN, int COUT, bool SBTOUT>
__global__ __launch_bounds__(256, 3) void conv_mfma_kernel(
    const u8* __restrict__ SBT, const u16* __restrict__ Agc,
    const float* __restrict__ bias, void* __restrict__ outp) {
  constexpr int NPHYS = CIN / 32;
  constexpr int NVIRT = 2 * NPHYS;
  constexpr int NCT = COUT / 64;
  constexpr int MT = 2;                    // 16-co tiles per wave
  constexpr int NT = 8;                    // l-positions per wave
  constexpr int GB = CIN / 8;
  constexpr int ABYTES = 3 * 64 * 32 * 2;  // 12288 per (virt,ct) A block
  constexpr int AW = ABYTES / 4;
  constexpr int AISS = AW / 1024;          // 3
  constexpr int BSTR = 40;                 // Bs row stride in u16 (80 B pad)
  __shared__ __align__(16) char lds[2 * ABYTES];   // A dbuf; epilogue reuses
  __shared__ __align__(16) u16 Bs[18 * 16 * BSTR]; // 23040 B expanded B tile

  int b = blockIdx.x, lb = blockIdx.y * 16, ct = blockIdx.z;
  int tid = threadIdx.x, lane = tid & 63, wid = tid >> 6;
  int wx = wid & 1, wy = wid >> 1;
  int q = lane >> 4, xx = lane & 15;
  int mloc = wy * 32;                      // co_local base for this wave
  int qs8 = (q ^ ((xx >> 1) & 3)) * 8;     // A swizzled granule offset (u16)

  f32x4 acc[MT][NT];
#pragma unroll
  for (int mt = 0; mt < MT; ++mt)
#pragma unroll
    for (int nt = 0; nt < NT; ++nt) acc[mt][nt] = (f32x4){0.f, 0.f, 0.f, 0.f};

  // staging-task helpers: task s in [0,288): row=s>>4, g=(s>>2)&3, tq=s&3
  auto stage_load = [&](int pn, int s) -> uint32_t {
    int row = s >> 4, g = (s >> 2) & 3, tq = s & 3;
    int l_in = lb + row - 1;
    if ((unsigned)l_in >= 128u) return 0u;
    return *(const uint32_t*)(SBT + ((size_t)(b * 128 + l_in) * GB + pn * 4 + g) * 16 + tq * 4);
  };
  auto stage_write = [&](int s, uint32_t w4) {
    int row = s >> 4, g = (s >> 2) & 3, tq = s & 3;
#pragma unroll
    for (int i = 0; i < 4; ++i) {
      uint32_t by = (w4 >> (8 * i)) & 0xFFu;
      int t = tq * 4 + i;
      *(uint4*)(Bs + (row * 16 + t) * BSTR + g * 8) = expandB4(by);
    }
  };

  // prologue: prefetch staging regs for chunk 0; issue A-DMA for v=0
  uint32_t w4a = stage_load(0, tid);
  uint32_t w4b = (tid < 32) ? stage_load(0, tid + 256) : 0u;
  {
    const char* gsrc = (const char*)Agc + (size_t)ct * ABYTES +
                       (size_t)wid * AW + lane * 16;
    char* ldst = lds + wid * AW;
#pragma unroll
    for (int i = 0; i < AISS; ++i) async_copy16(gsrc + i * 1024, ldst + i * 1024);
  }

  f16x8 Bf[10];
#pragma unroll 2
  for (int v = 0; v < NVIRT; ++v) {
    __syncthreads();  // drains A-DMA(v); separates Bs readers/writers
    if ((v & 1) == 0) {
      stage_write(tid, w4a);
      if (tid < 32) stage_write(tid + 256, w4b);
      __syncthreads();  // Bs visible to all waves
    }
    if (v + 1 < NVIRT) {  // issue A-DMA(v+1) (drained at next top barrier)
      const char* gsrc = (const char*)Agc + ((size_t)(v + 1) * NCT + ct) * ABYTES +
                         (size_t)wid * AW + lane * 16;
      char* ldst = lds + ((v + 1) & 1) * ABYTES + wid * AW;
#pragma unroll
      for (int i = 0; i < AISS; ++i) async_copy16(gsrc + i * 1024, ldst + i * 1024);
    }
    if ((v & 1) == 0) {
      int pn = (v >> 1) + 1;
      if (pn < NPHYS) {  // prefetch next chunk's staging u32s into regs
        w4a = stage_load(pn, tid);
        if (tid < 32) w4b = stage_load(pn, tid + 256);
      }
      // read this chunk's B fragments once; regs reused across both parts
#pragma unroll
      for (int u = 0; u < 10; ++u)
        Bf[u] = *(const f16x8*)(Bs + ((wx * 8 + u) * 16 + xx) * BSTR + q * 8);
    }
    const u16* Asv = (const u16*)(lds + (v & 1) * ABYTES);
#pragma unroll
    for (int tap = 0; tap < 3; ++tap)
#pragma unroll
      for (int mt = 0; mt < MT; ++mt) {
        f16x8 Af = *(const f16x8*)(Asv + ((size_t)(tap * 64 + mloc + mt * 16 + xx)) * 32 + qs8);
#pragma unroll
        for (int nt = 0; nt < NT; ++nt)
          acc[mt][nt] = __builtin_amdgcn_mfma_f32_16x16x32_f16(
              Af, Bf[nt + tap], acc[mt][nt], 0, 0, 0);
      }
  }
  __syncthreads();

  // epilogue: per-wave scr transpose (stride 19, <=2-way), 2 passes per mt
  float* scr = (float*)(void*)lds + wid * 1216;  // 64 rows x 19 words
  u16* bl = (u16*)(lds + 19456);                 // [64 co_local][16 l_local]
#pragma unroll
  for (int mt = 0; mt < MT; ++mt) {
#pragma unroll
    for (int h = 0; h < 2; ++h) {
#pragma unroll
      for (int u2 = 0; u2 < 4; ++u2)
#pragma unroll
        for (int r = 0; r < 4; ++r)
          scr[(u2 * 16 + q * 4 + r) * 19 + xx] = acc[mt][h * 4 + u2][r];
      __syncthreads();
      int col = mloc + mt * 16 + xx;
      float bc = bias[ct * 64 + col];
      const float* rowp = scr + (q * 16 + xx) * 19;
      float mm = 0.f, sp = 0.f;
      uint32_t bits = 0;
#pragma unroll
      for (int t = 0; t < 16; ++t) {
        float cur = rowp[t] + bc;
        mm = BETA * mm + cur - sp;
        bool s = mm > 1.0f;
        bits |= ((uint32_t)s) << t;
        sp = s ? 1.0f : 0.0f;
      }
      bl[col * 16 + wx * 8 + h * 4 + q] = (u16)bits;
      __syncthreads();
    }
  }

  if constexpr (SBTOUT) {
    constexpr int GBo = COUT / 8;   // full-row granule count
    if (tid < 128) {                // 8 g_local x 16 l
      int g = tid & 7, ll = tid >> 3;
      uint32_t wv[8];
#pragma unroll
      for (int j = 0; j < 8; ++j) wv[j] = bl[(8 * g + j) * 16 + ll];
      uint32_t ov[4];
#pragma unroll
      for (int k = 0; k < 4; ++k) {
        uint32_t v = 0;
#pragma unroll
        for (int tt = 0; tt < 4; ++tt) {
          int t = k * 4 + tt;
          uint32_t by = 0;
#pragma unroll
          for (int j = 0; j < 8; ++j) by |= ((wv[j] >> t) & 1u) << j;
          v |= by << (8 * tt);
        }
        ov[k] = v;
      }
      *(uint4*)((u8*)outp + ((size_t)(b * 128 + lb + ll) * GBo + ct * 8 + g) * 16) =
          make_uint4(ov[0], ov[1], ov[2], ov[3]);
    }
  } else {
    if (tid < 128) {  // 64 co x 2 halves of 8 l (16B each)
      int col = tid >> 1, hf = tid & 1;
      uint4 v = *(const uint4*)(bl + col * 16 + hf * 8);
      *(uint4*)((u16*)outp + ((size_t)b * COUT + ct * 64 + col) * 128 + lb + hf * 8) = v;
    }
  }
}

// ---------------------------------------------------------------------------
// head: conv4 (64->2) + LIF4, fc1 (256->100) + LIF5, fc2 accumulated (popcount)
// ---------------------------------------------------------------------------
__global__ __launch_bounds__(256) void head_kernel(
    const u16* __restrict__ s3bits, const float* __restrict__ W4,
    const float* __restrict__ b4, const float* __restrict__ fw1T,
    const float* __restrict__ fb1, const float* __restrict__ fw2T,
    const float* __restrict__ fb2, float* __restrict__ out) {
  __shared__ u16 s3l[64][130];
  __shared__ float W4l[384];
  __shared__ u16 flat4[256];
  __shared__ u16 s5b[100];
  int b = blockIdx.x, tid = threadIdx.x;

  for (int i = tid; i < 64 * 130; i += 256) {
    int ci = i / 130, idx = i % 130, lg = idx - 1;
    s3l[ci][idx] = (lg >= 0 && lg < 128) ? s3bits[((size_t)b * 64 + ci) * 128 + lg] : (u16)0;
  }
  for (int i = tid; i < 384; i += 256) W4l[i] = W4[i];
  __syncthreads();

  {
    int co = tid >> 7, l = tid & 127;
    float acc4[16];
#pragma unroll
    for (int t = 0; t < 16; ++t) acc4[t] = 0.f;
    for (int ci = 0; ci < 64; ++ci) {
#pragma unroll
      for (int k = 0; k < 3; ++k) {
        float wv = W4l[(co * 64 + ci) * 3 + k];
        uint32_t msk = s3l[ci][l + k];
#pragma unroll
        for (int t = 0; t < 16; ++t)
          acc4[t] = fmaf(wv, (float)((msk >> t) & 1u), acc4[t]);
      }
    }
    float bc = b4[co];
    float m = 0.f, sp = 0.f;
    uint32_t bits = 0;
#pragma unroll
    for (int t = 0; t < 16; ++t) {
      m = BETA * m + (acc4[t] + bc) - sp;
      bool s = m > 1.0f;
      bits |= ((uint32_t)s) << t;
      sp = s ? 1.0f : 0.0f;
    }
    flat4[tid] = (u16)bits;
  }
  __syncthreads();

  if (tid < 100) {
    float acc5[16];
#pragma unroll
    for (int t = 0; t < 16; ++t) acc5[t] = 0.f;
    for (int f = 0; f < 256; ++f) {
      float wv = fw1T[f * 100 + tid];
      uint32_t msk = flat4[f];
#pragma unroll
      for (int t = 0; t < 16; ++t)
        acc5[t] = fmaf(wv, (float)((msk >> t) & 1u), acc5[t]);
    }
    float bc = fb1[tid];
    float m = 0.f, sp = 0.f;
    uint32_t bits = 0;
#pragma unroll
    for (int t = 0; t < 16; ++t) {
      m = BETA * m + (acc5[t] + bc) - sp;
      bool s = m > 1.0f;
      bits |= ((uint32_t)s) << t;
      sp = s ? 1.0f : 0.0f;
    }
    s5b[tid] = (u16)bits;
  }
  __syncthreads();

  if (tid < 40) {
    float a = 0.f;
    for (int i = 0; i < 100; ++i) {
      float wv = fw2T[i * 40 + tid];
      a = fmaf(wv, (float)__popc((uint32_t)s5b[i]), a);
    }
    out[b * 40 + tid] = a * 0.0625f + fb2[tid];
  }
}

// ---------------------------------------------------------------------------
extern "C" void kernel_launch(void* const* d_in, const int* in_sizes, int n_in,
                              void* d_out, int out_size, void* d_ws, size_t ws_size,
                              hipStream_t stream) {
  const float* x   = (const float*)d_in[0];
  const float* W1  = (const float*)d_in[1];
  const float* b1  = (const float*)d_in[2];
  const float* W2  = (const float*)d_in[3];
  const float* b2  = (const float*)d_in[4];
  const float* W3  = (const float*)d_in[5];
  const float* b3  = (const float*)d_in[6];
  const float* W4  = (const float*)d_in[7];
  const float* b4  = (const float*)d_in[8];
  const float* fw1 = (const float*)d_in[9];
  const float* fb1 = (const float*)d_in[10];
  const float* fw2 = (const float*)d_in[11];
  const float* fb2 = (const float*)d_in[12];
  float* out = (float*)d_out;

  char* ws = (char*)d_ws;
  u16*   A2c  = (u16*)(ws);                       // 393216 B [virt][ct][tap][co64][ci32]
  u16*   A3c  = (u16*)(ws + 393216);              //  98304 B
  float* fw1T = (float*)(ws + 491520);            // 102400 B
  float* fw2T = (float*)(ws + 593920);            //  16000 B (pad to 610304)
  u8*    SBT2 = (u8*)(ws + 610304);               // 134217728 B [b][l][32][16]
  u8*    SBT3 = (u8*)(ws + 610304 + 134217728);   //  67108864 B [b][l][16][16]
  u16*   s3b  = (u16*)(ws + 610304 + 134217728 + 67108864);  // 33554432 B u16 [b][co][l]
  // total: 235,491,328 B

  prep_kernel<<<dim3(596), dim3(256), 0, stream>>>(W2, W3, fw1, fw2, A2c, A3c, fw1T, fw2T);
  conv1_lif_kernel<<<dim3(2048, 32), dim3(256), 0, stream>>>(x, W1, b1, SBT2);
  conv_mfma_kernel<256, 128, true><<<dim3(2048, 8, 2), dim3(256), 0, stream>>>(SBT2, A2c, b2, SBT3);
  conv_mfma_kernel<128, 64, false><<<dim3(2048, 8, 1), dim3(256), 0, stream>>>(SBT3, A3c, b3, s3b);
  head_kernel<<<dim3(2048), dim3(256), 0, stream>>>(s3b, W4, b4, fw1T, fb1, fw2T, fb2, out);
}

// Round 12
// 1947.610 us; speedup vs baseline: 1.0816x; 1.0494x over previous
//
#include <hip/hip_runtime.h>
#include <stdint.h>

#define BETA 0.9f

typedef unsigned short u16;
typedef unsigned char u8;
typedef signed char i8;
typedef int i32x4 __attribute__((ext_vector_type(4)));

// async global->LDS, 16B per lane; lds ptr is wave-uniform base (+lane*16 by HW)
__device__ __forceinline__ void async_copy16(const void* g, void* l) {
  __builtin_amdgcn_global_load_lds(
      (const __attribute__((address_space(1))) uint32_t*)g,
      (__attribute__((address_space(3))) uint32_t*)l, 16, 0, 0);
}

// ---------------------------------------------------------------------------
// prep: 3-way int8 fixed-point split of W2/W3 (r6 math, HW-verified exact):
//   d0 = rint(w*2^11); r1 = w - d0*2^-11
//   d1 = rint(r1*2^18); r2 = r1 - d1*2^-18
//   d2 = rint(r2*2^25); residual <= 2^-26
// |w| <= 0.0511 -> |d0| <= 105, |d1|,|d2| <= 64: all fit i8.
// Reconstruction: w*2^25 ~= ((d0<<7)+d1)<<7 + d2 (exact i32 fold).
// Layout A[part][cp][ct][tap][co64][ci64] i8; 12KB DMA blocks; granule
// (16 i8) XOR-swizzled by ((col>>1)&3) for conflict-free b128 LDS reads
// (bits 1-2 of local co come from lane xx). Also fc transposes.
// ---------------------------------------------------------------------------
__global__ void prep_kernel(const float* __restrict__ W2, const float* __restrict__ W3,
                            const float* __restrict__ fw1, const float* __restrict__ fw2,
                            i8* __restrict__ A2c, i8* __restrict__ A3c,
                            float* __restrict__ fw1T, float* __restrict__ fw2T) {
  int o = blockIdx.x * 256 + threadIdx.x;
  if (o < 98304) {  // W2: (tap, co, ci), 3*128*256
    int tap = o >> 15, r = o & 32767, co = r >> 8, ci = r & 255;
    float w = W2[(co * 256 + ci) * 3 + tap];
    float d0 = __builtin_rintf(w * 0x1p11f);
    float r1 = w - d0 * 0x1p-11f;
    float d1 = __builtin_rintf(r1 * 0x1p18f);
    float r2 = r1 - d1 * 0x1p-18f;
    float d2 = __builtin_rintf(r2 * 0x1p25f);
    int cp = ci >> 6, cl = ci & 63;
    int ct = co >> 6, col = co & 63;
    int gs = ((cl >> 4) ^ ((col >> 1) & 3)) & 3;
    int pos = gs * 16 + (cl & 15);
    // block index for (part p): ((p*4 + cp)*2 + ct); 12288 i8 per block
    size_t base = ((size_t)((0 * 4 + cp) * 2 + ct) * 3 + tap) * 64 * 64 + col * 64 + pos;
    size_t pstride = (size_t)4 * 2 * 3 * 64 * 64;  // 98304
    A2c[base] = (i8)(int)d0;
    A2c[pstride + base] = (i8)(int)d1;
    A2c[2 * pstride + base] = (i8)(int)d2;
  }
  int o2 = o - 98304;  // W3: (tap, co, ci), 3*64*128 (NCT=1)
  if (o2 >= 0 && o2 < 24576) {
    int tap = o2 >> 13, r = o2 & 8191, co = r >> 7, ci = r & 127;
    float w = W3[(co * 128 + ci) * 3 + tap];
    float d0 = __builtin_rintf(w * 0x1p11f);
    float r1 = w - d0 * 0x1p-11f;
    float d1 = __builtin_rintf(r1 * 0x1p18f);
    float r2 = r1 - d1 * 0x1p-18f;
    float d2 = __builtin_rintf(r2 * 0x1p25f);
    int cp = ci >> 6, cl = ci & 63;
    int gs = ((cl >> 4) ^ ((co >> 1) & 3)) & 3;
    int pos = gs * 16 + (cl & 15);
    size_t base = ((size_t)(0 * 2 + cp) * 3 + tap) * 64 * 64 + co * 64 + pos;
    size_t pstride = (size_t)2 * 3 * 64 * 64;  // 24576
    A3c[base] = (i8)(int)d0;
    A3c[pstride + base] = (i8)(int)d1;
    A3c[2 * pstride + base] = (i8)(int)d2;
  }
  int o3 = o - (98304 + 24576);
  if (o3 >= 0 && o3 < 25600) {
    int f = o3 / 100, i = o3 % 100;
    fw1T[o3] = fw1[i * 256 + f];
  }
  int o4 = o - (98304 + 24576 + 25600);
  if (o4 >= 0 && o4 < 4000) {
    int i = o4 / 40, j = o4 % 40;
    fw2T[o4] = fw2[j * 100 + i];
  }
}

// ---------------------------------------------------------------------------
// conv1 (2->256, K=5, pad=2) + LIF1; writes byte-transposed spikes
// SBT2[b][l][g][t] (byte = spikes of co in [8g,8g+8), bit j = co 8g+j).
// ---------------------------------------------------------------------------
__global__ __launch_bounds__(256) void conv1_lif_kernel(
    const float* __restrict__ x, const float* __restrict__ W1,
    const float* __restrict__ b1, u8* __restrict__ SBT2) {
  __shared__ float xl[2][132];
  __shared__ u16 bl[8][128];
  int b = blockIdx.x, g = blockIdx.y;
  int tid = threadIdx.x;
  for (int i = tid; i < 264; i += 256) {
    int ci = i / 132, idx = i % 132, lg = idx - 2;
    xl[ci][idx] = (lg >= 0 && lg < 128) ? x[(b * 2 + ci) * 128 + lg] : 0.0f;
  }
  __syncthreads();
  int cosub = tid >> 5, tx = tid & 31;
  int co = g * 8 + cosub;
  float w[2][5];
#pragma unroll
  for (int ci = 0; ci < 2; ++ci)
#pragma unroll
    for (int k = 0; k < 5; ++k) w[ci][k] = W1[(co * 2 + ci) * 5 + k];
  float bias = b1[co];
  float cur[4];
#pragma unroll
  for (int j = 0; j < 4; ++j) {
    float acc = bias;
#pragma unroll
    for (int ci = 0; ci < 2; ++ci)
#pragma unroll
      for (int k = 0; k < 5; ++k) acc += w[ci][k] * xl[ci][4 * tx + j + k];
    cur[j] = acc;
  }
  float m[4] = {0.f, 0.f, 0.f, 0.f}, sp[4] = {0.f, 0.f, 0.f, 0.f};
  uint32_t bits[4] = {0u, 0u, 0u, 0u};
#pragma unroll
  for (int t = 0; t < 16; ++t) {
#pragma unroll
    for (int j = 0; j < 4; ++j) {
      m[j] = BETA * m[j] + cur[j] - sp[j];
      bool s = m[j] > 1.0f;
      bits[j] |= ((uint32_t)s) << t;
      sp[j] = s ? 1.0f : 0.0f;
    }
  }
#pragma unroll
  for (int j = 0; j < 4; ++j) bl[cosub][4 * tx + j] = (u16)bits[j];
  __syncthreads();
  if (tid < 128) {
    int l = tid;
    uint32_t wv[8];
#pragma unroll
    for (int j = 0; j < 8; ++j) wv[j] = bl[j][l];
    uint32_t ov[4];
#pragma unroll
    for (int k = 0; k < 4; ++k) {
      uint32_t v = 0;
#pragma unroll
      for (int tt = 0; tt < 4; ++tt) {
        int t = k * 4 + tt;
        uint32_t by = 0;
#pragma unroll
        for (int j = 0; j < 8; ++j) by |= ((wv[j] >> t) & 1u) << j;
        v |= by << (8 * tt);
      }
      ov[k] = v;
    }
    *(uint4*)(SBT2 + ((size_t)(b * 128 + l) * 32 + g) * 16) =
        make_uint4(ov[0], ov[1], ov[2], ov[3]);
  }
}

// ---------------------------------------------------------------------------
// i8 MFMA conv (CIN->COUT, K=3, pad=1) + LIF.
// Part-major over the 3-way i8 split; ONE i32 acc, exact <<7 folds at part
// boundaries (order-independent integer math -> bit-exact).
// Block: 64 co (z) x 16 l (y); waves 2x2 (wy: 32-co, wx: 8-l); MT=2, NT=8.
// A: async dbuf LDS (12KB = 3 taps x 64co x 64ci i8), one block per
//    (part, chunk-pair); r7 granule swizzle -> conflict-free b128 reads.
// B: per v, 256 threads expand the chunk-pair's 2304 spike bytes into LDS
//    i8 tile Bs[(row*16+t)][80] (b64 writes cover all 32 banks per 16-lane
//    phase; b128 reads perfect); sources register-prefetched one v ahead.
// MFMA 16x16x64_i8: lane(q,xx): A[m=xx][k=q*16+j], B[k=q*16+j][n=xx=t],
// D[m=q*4+r][n=xx].
// ---------------------------------------------------------------------------
template <int CIN, int COUT, bool SBTOUT>
__global__ __launch_bounds__(256, 3) void conv_mfma_kernel(
    const u8* __restrict__ SBT, const i8* __restrict__ Agc,
    const float* __restrict__ bias, void* __restrict__ outp) {
  constexpr int NCP = CIN / 64;            // chunk-pairs (64-ci units)
  constexpr int NVIRT = 3 * NCP;           // part-major virtual blocks
  constexpr int NCT = COUT / 64;
  constexpr int MT = 2;                    // 16-co tiles per wave
  constexpr int NT = 8;                    // l-positions per wave
  constexpr int GB = CIN / 8;
  constexpr int ABYTES = 3 * 64 * 64;      // 12288 per (part,cp,ct) A block
  constexpr int AW = ABYTES / 4;
  constexpr int AISS = AW / 1024;          // 3
  __shared__ __align__(16) char lds[2 * ABYTES];   // A dbuf; epilogue reuses
  __shared__ __align__(16) u8 Bs[18 * 16 * 80];    // 23040 B i8 0/1 tile

  int b = blockIdx.x, lb = blockIdx.y * 16, ct = blockIdx.z;
  int tid = threadIdx.x, lane = tid & 63, wid = tid >> 6;
  int wx = wid & 1, wy = wid >> 1;
  int q = lane >> 4, xx = lane & 15;
  int mloc = wy * 32;                      // co_local base for this wave
  int gs16 = ((q ^ ((xx >> 1) & 3)) & 3) * 16;  // A swizzled granule (bytes)

  i32x4 acc[MT][NT];
#pragma unroll
  for (int mt = 0; mt < MT; ++mt)
#pragma unroll
    for (int nt = 0; nt < NT; ++nt) acc[mt][nt] = (i32x4){0, 0, 0, 0};

  // staging tasks s in [0,576): row = s>>5 (18), tq = (s>>3)&3, gl = s&7
  auto stage_load = [&](int cp, int s) -> uint32_t {
    int row = s >> 5, gl = s & 7, tq = (s >> 3) & 3;
    int l_in = lb + row - 1;
    if ((unsigned)l_in >= 128u) return 0u;
    return *(const uint32_t*)(SBT + ((size_t)(b * 128 + l_in) * GB + cp * 8 + gl) * 16 + tq * 4);
  };
  auto stage_write = [&](int s, uint32_t w4) {
    int row = s >> 5, gl = s & 7, tq = (s >> 3) & 3;
#pragma unroll
    for (int i = 0; i < 4; ++i) {
      uint32_t by = (w4 >> (8 * i)) & 0xFFu;
      uint32_t lo = ((by & 0xFu) * 0x204081u) & 0x01010101u;
      uint32_t hi = ((by >> 4) * 0x204081u) & 0x01010101u;
      int t = tq * 4 + i;
      *(uint2*)(Bs + (row * 16 + t) * 80 + gl * 8) = make_uint2(lo, hi);
    }
  };

  // prologue: prefetch staging sources for cp 0; issue A-DMA for v=0
  uint32_t w4a = stage_load(0, tid);
  uint32_t w4b = stage_load(0, tid + 256);
  uint32_t w4c = (tid < 64) ? stage_load(0, tid + 512) : 0u;
  {
    const char* gsrc = (const char*)Agc + (size_t)ct * ABYTES +
                       (size_t)wid * AW + lane * 16;
    char* ldst = lds + wid * AW;
#pragma unroll
    for (int i = 0; i < AISS; ++i) async_copy16(gsrc + i * 1024, ldst + i * 1024);
  }

  for (int v = 0; v < NVIRT; ++v) {
    __syncthreads();  // drains A-DMA(v)+source loads; prev Bs readers done
    stage_write(tid, w4a);
    stage_write(tid + 256, w4b);
    if (tid < 64) stage_write(tid + 512, w4c);
    __syncthreads();  // Bs(v) visible to all waves
    if (v + 1 < NVIRT) {
      // issue A-DMA(v+1) into the other buffer (drained at next top barrier)
      const char* gsrc = (const char*)Agc + ((size_t)(v + 1) * NCT + ct) * ABYTES +
                         (size_t)wid * AW + lane * 16;
      char* ldst = lds + ((v + 1) & 1) * ABYTES + wid * AW;
#pragma unroll
      for (int i = 0; i < AISS; ++i) async_copy16(gsrc + i * 1024, ldst + i * 1024);
      // prefetch next v's staging sources into regs (L2-hot on re-passes)
      int cpn = (v + 1) % NCP;
      w4a = stage_load(cpn, tid);
      w4b = stage_load(cpn, tid + 256);
      if (tid < 64) w4c = stage_load(cpn, tid + 512);
    }
    if (v > 0 && (v % NCP) == 0) {  // part boundary: exact fold
#pragma unroll
      for (int mt = 0; mt < MT; ++mt)
#pragma unroll
        for (int nt = 0; nt < NT; ++nt) acc[mt][nt] = acc[mt][nt] << 7;
    }
    // read this v's B fragments (10 rows, b128, conflict-free)
    i32x4 Bf[10];
#pragma unroll
    for (int u = 0; u < 10; ++u)
      Bf[u] = *(const i32x4*)(Bs + ((wx * 8 + u) * 16 + xx) * 80 + q * 16);
    const i8* Asv = (const i8*)(lds + (v & 1) * ABYTES);
#pragma unroll
    for (int tap = 0; tap < 3; ++tap)
#pragma unroll
      for (int mt = 0; mt < MT; ++mt) {
        i32x4 Af = *(const i32x4*)(Asv + (tap * 64 + mloc + mt * 16 + xx) * 64 + gs16);
#pragma unroll
        for (int nt = 0; nt < NT; ++nt)
          acc[mt][nt] = __builtin_amdgcn_mfma_i32_16x16x64_i8(
              Af, Bf[nt + tap], acc[mt][nt], 0, 0, 0);
      }
  }
  __syncthreads();

  // epilogue: scale 2^-25, per-wave scr transpose (stride 19), LIF, pack
  float* scr = (float*)(void*)lds + wid * 1216;  // 64 rows x 19 words
  u16* bl = (u16*)(lds + 19456);                 // [64 co_local][16 l_local]
#pragma unroll
  for (int mt = 0; mt < MT; ++mt) {
#pragma unroll
    for (int h = 0; h < 2; ++h) {
#pragma unroll
      for (int u2 = 0; u2 < 4; ++u2)
#pragma unroll
        for (int r = 0; r < 4; ++r)
          scr[(u2 * 16 + q * 4 + r) * 19 + xx] =
              (float)acc[mt][h * 4 + u2][r] * 0x1p-25f;
      __syncthreads();
      int col = mloc + mt * 16 + xx;
      float bc = bias[ct * 64 + col];
      const float* rowp = scr + (q * 16 + xx) * 19;
      float mm = 0.f, sp = 0.f;
      uint32_t bits = 0;
#pragma unroll
      for (int t = 0; t < 16; ++t) {
        float cur = rowp[t] + bc;
        mm = BETA * mm + cur - sp;
        bool s = mm > 1.0f;
        bits |= ((uint32_t)s) << t;
        sp = s ? 1.0f : 0.0f;
      }
      bl[col * 16 + wx * 8 + h * 4 + q] = (u16)bits;
      __syncthreads();
    }
  }

  if constexpr (SBTOUT) {
    constexpr int GBo = COUT / 8;   // full-row granule count
    if (tid < 128) {                // 8 g_local x 16 l
      int g = tid & 7, ll = tid >> 3;
      uint32_t wv[8];
#pragma unroll
      for (int j = 0; j < 8; ++j) wv[j] = bl[(8 * g + j) * 16 + ll];
      uint32_t ov[4];
#pragma unroll
      for (int k = 0; k < 4; ++k) {
        uint32_t v = 0;
#pragma unroll
        for (int tt = 0; tt < 4; ++tt) {
          int t = k * 4 + tt;
          uint32_t by = 0;
#pragma unroll
          for (int j = 0; j < 8; ++j) by |= ((wv[j] >> t) & 1u) << j;
          v |= by << (8 * tt);
        }
        ov[k] = v;
      }
      *(uint4*)((u8*)outp + ((size_t)(b * 128 + lb + ll) * GBo + ct * 8 + g) * 16) =
          make_uint4(ov[0], ov[1], ov[2], ov[3]);
    }
  } else {
    if (tid < 128) {  // 64 co x 2 halves of 8 l (16B each)
      int col = tid >> 1, hf = tid & 1;
      uint4 v = *(const uint4*)(bl + col * 16 + hf * 8);
      *(uint4*)((u16*)outp + ((size_t)b * COUT + ct * 64 + col) * 128 + lb + hf * 8) = v;
    }
  }
}

// ---------------------------------------------------------------------------
// head: conv4 (64->2) + LIF4, fc1 (256->100) + LIF5, fc2 accumulated (popcount)
// ---------------------------------------------------------------------------
__global__ __launch_bounds__(256) void head_kernel(
    const u16* __restrict__ s3bits, const float* __restrict__ W4,
    const float* __restrict__ b4, const float* __restrict__ fw1T,
    const float* __restrict__ fb1, const float* __restrict__ fw2T,
    const float* __restrict__ fb2, float* __restrict__ out) {
  __shared__ u16 s3l[64][130];
  __shared__ float W4l[384];
  __shared__ u16 flat4[256];
  __shared__ u16 s5b[100];
  int b = blockIdx.x, tid = threadIdx.x;

  for (int i = tid; i < 64 * 130; i += 256) {
    int ci = i / 130, idx = i % 130, lg = idx - 1;
    s3l[ci][idx] = (lg >= 0 && lg < 128) ? s3bits[((size_t)b * 64 + ci) * 128 + lg] : (u16)0;
  }
  for (int i = tid; i < 384; i += 256) W4l[i] = W4[i];
  __syncthreads();

  {
    int co = tid >> 7, l = tid & 127;
    float acc4[16];
#pragma unroll
    for (int t = 0; t < 16; ++t) acc4[t] = 0.f;
    for (int ci = 0; ci < 64; ++ci) {
#pragma unroll
      for (int k = 0; k < 3; ++k) {
        float wv = W4l[(co * 64 + ci) * 3 + k];
        uint32_t msk = s3l[ci][l + k];
#pragma unroll
        for (int t = 0; t < 16; ++t)
          acc4[t] = fmaf(wv, (float)((msk >> t) & 1u), acc4[t]);
      }
    }
    float bc = b4[co];
    float m = 0.f, sp = 0.f;
    uint32_t bits = 0;
#pragma unroll
    for (int t = 0; t < 16; ++t) {
      m = BETA * m + (acc4[t] + bc) - sp;
      bool s = m > 1.0f;
      bits |= ((uint32_t)s) << t;
      sp = s ? 1.0f : 0.0f;
    }
    flat4[tid] = (u16)bits;
  }
  __syncthreads();

  if (tid < 100) {
    float acc5[16];
#pragma unroll
    for (int t = 0; t < 16; ++t) acc5[t] = 0.f;
    for (int f = 0; f < 256; ++f) {
      float wv = fw1T[f * 100 + tid];
      uint32_t msk = flat4[f];
#pragma unroll
      for (int t = 0; t < 16; ++t)
        acc5[t] = fmaf(wv, (float)((msk >> t) & 1u), acc5[t]);
    }
    float bc = fb1[tid];
    float m = 0.f, sp = 0.f;
    uint32_t bits = 0;
#pragma unroll
    for (int t = 0; t < 16; ++t) {
      m = BETA * m + (acc5[t] + bc) - sp;
      bool s = m > 1.0f;
      bits |= ((uint32_t)s) << t;
      sp = s ? 1.0f : 0.0f;
    }
    s5b[tid] = (u16)bits;
  }
  __syncthreads();

  if (tid < 40) {
    float a = 0.f;
    for (int i = 0; i < 100; ++i) {
      float wv = fw2T[i * 40 + tid];
      a = fmaf(wv, (float)__popc((uint32_t)s5b[i]), a);
    }
    out[b * 40 + tid] = a * 0.0625f + fb2[tid];
  }
}

// ---------------------------------------------------------------------------
extern "C" void kernel_launch(void* const* d_in, const int* in_sizes, int n_in,
                              void* d_out, int out_size, void* d_ws, size_t ws_size,
                              hipStream_t stream) {
  const float* x   = (const float*)d_in[0];
  const float* W1  = (const float*)d_in[1];
  const float* b1  = (const float*)d_in[2];
  const float* W2  = (const float*)d_in[3];
  const float* b2  = (const float*)d_in[4];
  const float* W3  = (const float*)d_in[5];
  const float* b3  = (const float*)d_in[6];
  const float* W4  = (const float*)d_in[7];
  const float* b4  = (const float*)d_in[8];
  const float* fw1 = (const float*)d_in[9];
  const float* fb1 = (const float*)d_in[10];
  const float* fw2 = (const float*)d_in[11];
  const float* fb2 = (const float*)d_in[12];
  float* out = (float*)d_out;

  char* ws = (char*)d_ws;
  i8*    A2c  = (i8*)(ws);                        // 294912 B [part][cp][ct][tap][co64][ci64]
  i8*    A3c  = (i8*)(ws + 294912);               //  73728 B
  float* fw1T = (float*)(ws + 368640);            // 102400 B
  float* fw2T = (float*)(ws + 471040);            //  16000 B (pad to 487424)
  u8*    SBT2 = (u8*)(ws + 487424);               // 134217728 B [b][l][32][16]
  u8*    SBT3 = (u8*)(ws + 487424 + 134217728);   //  67108864 B [b][l][16][16]
  u16*   s3b  = (u16*)(ws + 487424 + 134217728 + 67108864);  // 33554432 B u16 [b][co][l]
  // total: 235,368,448 B

  prep_kernel<<<dim3(596), dim3(256), 0, stream>>>(W2, W3, fw1, fw2, A2c, A3c, fw1T, fw2T);
  conv1_lif_kernel<<<dim3(2048, 32), dim3(256), 0, stream>>>(x, W1, b1, SBT2);
  conv_mfma_kernel<256, 128, true><<<dim3(2048, 8, 2), dim3(256), 0, stream>>>(SBT2, A2c, b2, SBT3);
  conv_mfma_kernel<128, 64, false><<<dim3(2048, 8, 1), dim3(256), 0, stream>>>(SBT3, A3c, b3, s3b);
  head_kernel<<<dim3(2048), dim3(256), 0, stream>>>(s3b, W4, b4, fw1T, fb1, fw2T, fb2, out);
}

// Round 13
// 1849.783 us; speedup vs baseline: 1.1388x; 1.0529x over previous
//
#include <hip/hip_runtime.h>
#include <stdint.h>

#define BETA 0.9f

typedef unsigned short u16;
typedef unsigned char u8;
typedef signed char i8;
typedef int i32x4 __attribute__((ext_vector_type(4)));

// async global->LDS, 16B per lane; lds ptr is wave-uniform base (+lane*16 by HW)
__device__ __forceinline__ void async_copy16(const void* g, void* l) {
  __builtin_amdgcn_global_load_lds(
      (const __attribute__((address_space(1))) uint32_t*)g,
      (__attribute__((address_space(3))) uint32_t*)l, 16, 0, 0);
}

// ---------------------------------------------------------------------------
// prep: 3-way int8 fixed-point split of W2/W3 (HW-verified exact, r6/r12):
//   d0 = rint(w*2^11); d1 = rint(r1*2^18); d2 = rint(r2*2^25); res <= 2^-26
// Reconstruction: w*2^25 ~= ((d0<<7)+d1)<<7 + d2 (exact i32 fold).
// Layout A[part][cp][ct][tap][co64][ci64] i8; 12KB DMA blocks; 16-i8 granule
// XOR-swizzled by ((col>>1)&3) for conflict-free b128 LDS reads.
// ---------------------------------------------------------------------------
__global__ void prep_kernel(const float* __restrict__ W2, const float* __restrict__ W3,
                            const float* __restrict__ fw1, const float* __restrict__ fw2,
                            i8* __restrict__ A2c, i8* __restrict__ A3c,
                            float* __restrict__ fw1T, float* __restrict__ fw2T) {
  int o = blockIdx.x * 256 + threadIdx.x;
  if (o < 98304) {  // W2: (tap, co, ci), 3*128*256
    int tap = o >> 15, r = o & 32767, co = r >> 8, ci = r & 255;
    float w = W2[(co * 256 + ci) * 3 + tap];
    float d0 = __builtin_rintf(w * 0x1p11f);
    float r1 = w - d0 * 0x1p-11f;
    float d1 = __builtin_rintf(r1 * 0x1p18f);
    float r2 = r1 - d1 * 0x1p-18f;
    float d2 = __builtin_rintf(r2 * 0x1p25f);
    int cp = ci >> 6, cl = ci & 63;
    int ct = co >> 6, col = co & 63;
    int gs = ((cl >> 4) ^ ((col >> 1) & 3)) & 3;
    int pos = gs * 16 + (cl & 15);
    size_t base = ((size_t)((0 * 4 + cp) * 2 + ct) * 3 + tap) * 64 * 64 + col * 64 + pos;
    size_t pstride = (size_t)4 * 2 * 3 * 64 * 64;  // 98304
    A2c[base] = (i8)(int)d0;
    A2c[pstride + base] = (i8)(int)d1;
    A2c[2 * pstride + base] = (i8)(int)d2;
  }
  int o2 = o - 98304;  // W3: (tap, co, ci), 3*64*128 (NCT=1)
  if (o2 >= 0 && o2 < 24576) {
    int tap = o2 >> 13, r = o2 & 8191, co = r >> 7, ci = r & 127;
    float w = W3[(co * 128 + ci) * 3 + tap];
    float d0 = __builtin_rintf(w * 0x1p11f);
    float r1 = w - d0 * 0x1p-11f;
    float d1 = __builtin_rintf(r1 * 0x1p18f);
    float r2 = r1 - d1 * 0x1p-18f;
    float d2 = __builtin_rintf(r2 * 0x1p25f);
    int cp = ci >> 6, cl = ci & 63;
    int gs = ((cl >> 4) ^ ((co >> 1) & 3)) & 3;
    int pos = gs * 16 + (cl & 15);
    size_t base = ((size_t)(0 * 2 + cp) * 3 + tap) * 64 * 64 + co * 64 + pos;
    size_t pstride = (size_t)2 * 3 * 64 * 64;  // 24576
    A3c[base] = (i8)(int)d0;
    A3c[pstride + base] = (i8)(int)d1;
    A3c[2 * pstride + base] = (i8)(int)d2;
  }
  int o3 = o - (98304 + 24576);
  if (o3 >= 0 && o3 < 25600) {
    int f = o3 / 100, i = o3 % 100;
    fw1T[o3] = fw1[i * 256 + f];
  }
  int o4 = o - (98304 + 24576 + 25600);
  if (o4 >= 0 && o4 < 4000) {
    int i = o4 / 40, j = o4 % 40;
    fw2T[o4] = fw2[j * 100 + i];
  }
}

// ---------------------------------------------------------------------------
// conv1 (2->256, K=5, pad=2) + LIF1; writes byte-transposed spikes
// SBT2[b][l][g][t] (byte = spikes of co in [8g,8g+8), bit j = co 8g+j).
// ---------------------------------------------------------------------------
__global__ __launch_bounds__(256) void conv1_lif_kernel(
    const float* __restrict__ x, const float* __restrict__ W1,
    const float* __restrict__ b1, u8* __restrict__ SBT2) {
  __shared__ float xl[2][132];
  __shared__ u16 bl[8][128];
  int b = blockIdx.x, g = blockIdx.y;
  int tid = threadIdx.x;
  for (int i = tid; i < 264; i += 256) {
    int ci = i / 132, idx = i % 132, lg = idx - 2;
    xl[ci][idx] = (lg >= 0 && lg < 128) ? x[(b * 2 + ci) * 128 + lg] : 0.0f;
  }
  __syncthreads();
  int cosub = tid >> 5, tx = tid & 31;
  int co = g * 8 + cosub;
  float w[2][5];
#pragma unroll
  for (int ci = 0; ci < 2; ++ci)
#pragma unroll
    for (int k = 0; k < 5; ++k) w[ci][k] = W1[(co * 2 + ci) * 5 + k];
  float bias = b1[co];
  float cur[4];
#pragma unroll
  for (int j = 0; j < 4; ++j) {
    float acc = bias;
#pragma unroll
    for (int ci = 0; ci < 2; ++ci)
#pragma unroll
      for (int k = 0; k < 5; ++k) acc += w[ci][k] * xl[ci][4 * tx + j + k];
    cur[j] = acc;
  }
  float m[4] = {0.f, 0.f, 0.f, 0.f}, sp[4] = {0.f, 0.f, 0.f, 0.f};
  uint32_t bits[4] = {0u, 0u, 0u, 0u};
#pragma unroll
  for (int t = 0; t < 16; ++t) {
#pragma unroll
    for (int j = 0; j < 4; ++j) {
      m[j] = BETA * m[j] + cur[j] - sp[j];
      bool s = m[j] > 1.0f;
      bits[j] |= ((uint32_t)s) << t;
      sp[j] = s ? 1.0f : 0.0f;
    }
  }
#pragma unroll
  for (int j = 0; j < 4; ++j) bl[cosub][4 * tx + j] = (u16)bits[j];
  __syncthreads();
  if (tid < 128) {
    int l = tid;
    uint32_t wv[8];
#pragma unroll
    for (int j = 0; j < 8; ++j) wv[j] = bl[j][l];
    uint32_t ov[4];
#pragma unroll
    for (int k = 0; k < 4; ++k) {
      uint32_t v = 0;
#pragma unroll
      for (int tt = 0; tt < 4; ++tt) {
        int t = k * 4 + tt;
        uint32_t by = 0;
#pragma unroll
        for (int j = 0; j < 8; ++j) by |= ((wv[j] >> t) & 1u) << j;
        v |= by << (8 * tt);
      }
      ov[k] = v;
    }
    *(uint4*)(SBT2 + ((size_t)(b * 128 + l) * 32 + g) * 16) =
        make_uint4(ov[0], ov[1], ov[2], ov[3]);
  }
}

// ---------------------------------------------------------------------------
// i8 MFMA conv (CIN->COUT, K=3, pad=1) + LIF.   [r12 + LUT + boustrophedon]
// Part-major i8 3-split, single i32 acc, exact <<7 folds (bit-exact).
// Boustrophedon cp order (p0:0..NCP-1, p1:reversed, p2:forward): cp repeats
// at part boundaries -> staging + Bf re-read + barrier skipped there
// (2/12 conv2, 2/6 conv3). Fold points coincide with the skips.
// B expansion via 256x8B LDS LUT (bfe + b64 read/write, no mul-spread).
// A: async dbuf LDS 12KB/block, r7 granule swizzle.  3 blocks/CU.
// ---------------------------------------------------------------------------
template <int CIN, int COUT, bool SBTOUT>
__global__ __launch_bounds__(256, 3) void conv_mfma_kernel(
    const u8* __restrict__ SBT, const i8* __restrict__ Agc,
    const float* __restrict__ bias, void* __restrict__ outp) {
  constexpr int NCP = CIN / 64;            // chunk-pairs (64-ci units)
  constexpr int LNCP = (NCP == 4) ? 2 : 1;
  constexpr int NVIRT = 3 * NCP;
  constexpr int NCT = COUT / 64;
  constexpr int MT = 2, NT = 8;
  constexpr int GB = CIN / 8;
  constexpr int ABYTES = 3 * 64 * 64;      // 12288 per (part,cp,ct) A block
  constexpr int AW = ABYTES / 4;
  constexpr int AISS = AW / 1024;          // 3
  __shared__ __align__(16) char lds[2 * ABYTES];   // A dbuf; epilogue reuses
  __shared__ __align__(16) u8 Bs[18 * 16 * 80];    // 23040 B i8 0/1 tile
  __shared__ __align__(8) uint2 LUT[256];          // byte -> 8 i8 bits

  int b = blockIdx.x, lb = blockIdx.y * 16, ct = blockIdx.z;
  int tid = threadIdx.x, lane = tid & 63, wid = tid >> 6;
  int wx = wid & 1, wy = wid >> 1;
  int q = lane >> 4, xx = lane & 15;
  int mloc = wy * 32;
  int gs16 = ((q ^ ((xx >> 1) & 3)) & 3) * 16;  // A swizzled granule (bytes)

  // build LUT (visible after the v=0 top barrier)
  {
    uint32_t by = tid;
    uint32_t lo = ((by & 0xFu) * 0x204081u) & 0x01010101u;
    uint32_t hi = (((by >> 4) & 0xFu) * 0x204081u) & 0x01010101u;
    LUT[tid] = make_uint2(lo, hi);
  }

  i32x4 acc[MT][NT];
#pragma unroll
  for (int mt = 0; mt < MT; ++mt)
#pragma unroll
    for (int nt = 0; nt < NT; ++nt) acc[mt][nt] = (i32x4){0, 0, 0, 0};

  // staging tasks s in [0,576): row = s>>5 (18), tq = (s>>3)&3, gl = s&7
  // hoisted per-thread source bases (+cp*128 per chunk-pair)
  auto mkbase = [&](int s, const u8*& ptr, bool& vf) {
    int row = s >> 5, gl = s & 7, tq = (s >> 3) & 3;
    int l_in = lb + row - 1;
    vf = ((unsigned)l_in < 128u);
    int l_c = vf ? l_in : 0;
    ptr = SBT + ((size_t)(b * 128 + l_c) * GB + gl) * 16 + tq * 4;
  };
  const u8 *sp0, *sp1, *sp2 = nullptr;
  bool f0, f1, f2 = false;
  mkbase(tid, sp0, f0);
  mkbase(tid + 256, sp1, f1);
  if (tid < 64) mkbase(tid + 512, sp2, f2);

  auto stage_write = [&](int s, uint32_t w4) {
    int row = s >> 5, gl = s & 7, tq = (s >> 3) & 3;
    u8* dst = Bs + (row * 16 + tq * 4) * 80 + gl * 8;
#pragma unroll
    for (int i = 0; i < 4; ++i)
      *(uint2*)(dst + i * 80) = LUT[(w4 >> (8 * i)) & 0xFFu];
  };

  auto ablock = [&](int v) -> size_t {
    int p = v >> LNCP, j = v & (NCP - 1);
    int cp = (p & 1) ? (NCP - 1 - j) : j;
    return ((size_t)(p * NCP + cp) * NCT + ct) * (size_t)ABYTES;
  };

  // prologue: staging sources for cp 0; A-DMA for v=0
  uint32_t w4a = f0 ? *(const uint32_t*)sp0 : 0u;
  uint32_t w4b = f1 ? *(const uint32_t*)sp1 : 0u;
  uint32_t w4c = (tid < 64 && f2) ? *(const uint32_t*)sp2 : 0u;
  {
    const char* gsrc = (const char*)Agc + (size_t)wid * AW + lane * 16 + ablock(0);
    char* ldst = lds + wid * AW;
#pragma unroll
    for (int i = 0; i < AISS; ++i) async_copy16(gsrc + i * 1024, ldst + i * 1024);
  }

  i32x4 Bf[10];
  for (int v = 0; v < NVIRT; ++v) {
    int p = v >> LNCP, j = v & (NCP - 1);
    bool stg = (v == 0) || (j != 0);
    __syncthreads();  // drains A-DMA(v); prev Bs readers done
    if (stg) {
      stage_write(tid, w4a);
      stage_write(tid + 256, w4b);
      if (tid < 64) stage_write(tid + 512, w4c);
      __syncthreads();  // Bs(v) visible
    }
    if (v + 1 < NVIRT) {
      const char* gsrc = (const char*)Agc + (size_t)wid * AW + lane * 16 + ablock(v + 1);
      char* ldst = lds + ((v + 1) & 1) * ABYTES + wid * AW;
#pragma unroll
      for (int i = 0; i < AISS; ++i) async_copy16(gsrc + i * 1024, ldst + i * 1024);
    }
    if (stg) {
      // prefetch sources for the NEXT staged cp (skips land on j==0 repeats)
      int jn = j + 1, pn = p;
      if (jn == NCP) { pn = p + 1; jn = 1; }
      if (pn < 3) {
        int cpn = (pn & 1) ? (NCP - 1 - jn) : jn;
        w4a = f0 ? *(const uint32_t*)(sp0 + cpn * 128) : 0u;
        w4b = f1 ? *(const uint32_t*)(sp1 + cpn * 128) : 0u;
        if (tid < 64) w4c = f2 ? *(const uint32_t*)(sp2 + cpn * 128) : 0u;
      }
      // (re)read B fragments; regs persist across the skip iterations
#pragma unroll
      for (int u = 0; u < 10; ++u)
        Bf[u] = *(const i32x4*)(Bs + ((wx * 8 + u) * 16 + xx) * 80 + q * 16);
    }
    if (j == 0 && p > 0) {  // part boundary: exact fold
#pragma unroll
      for (int mt = 0; mt < MT; ++mt)
#pragma unroll
        for (int nt = 0; nt < NT; ++nt) acc[mt][nt] = acc[mt][nt] << 7;
    }
    const i8* Asv = (const i8*)(lds + (v & 1) * ABYTES);
#pragma unroll
    for (int tap = 0; tap < 3; ++tap)
#pragma unroll
      for (int mt = 0; mt < MT; ++mt) {
        i32x4 Af = *(const i32x4*)(Asv + (tap * 64 + mloc + mt * 16 + xx) * 64 + gs16);
#pragma unroll
        for (int nt = 0; nt < NT; ++nt)
          acc[mt][nt] = __builtin_amdgcn_mfma_i32_16x16x64_i8(
              Af, Bf[nt + tap], acc[mt][nt], 0, 0, 0);
      }
  }
  __syncthreads();

  // epilogue: scale 2^-25, per-wave scr transpose (stride 19), LIF, pack
  float* scr = (float*)(void*)lds + wid * 1216;  // 64 rows x 19 words
  u16* bl = (u16*)(lds + 19456);                 // [64 co_local][16 l_local]
#pragma unroll
  for (int mt = 0; mt < MT; ++mt) {
#pragma unroll
    for (int h = 0; h < 2; ++h) {
#pragma unroll
      for (int u2 = 0; u2 < 4; ++u2)
#pragma unroll
        for (int r = 0; r < 4; ++r)
          scr[(u2 * 16 + q * 4 + r) * 19 + xx] =
              (float)acc[mt][h * 4 + u2][r] * 0x1p-25f;
      __syncthreads();
      int col = mloc + mt * 16 + xx;
      float bc = bias[ct * 64 + col];
      const float* rowp = scr + (q * 16 + xx) * 19;
      float mm = 0.f, sp = 0.f;
      uint32_t bits = 0;
#pragma unroll
      for (int t = 0; t < 16; ++t) {
        float cur = rowp[t] + bc;
        mm = BETA * mm + cur - sp;
        bool s = mm > 1.0f;
        bits |= ((uint32_t)s) << t;
        sp = s ? 1.0f : 0.0f;
      }
      bl[col * 16 + wx * 8 + h * 4 + q] = (u16)bits;
      __syncthreads();
    }
  }

  if constexpr (SBTOUT) {
    constexpr int GBo = COUT / 8;
    if (tid < 128) {  // 8 g_local x 16 l
      int g = tid & 7, ll = tid >> 3;
      uint32_t wv[8];
#pragma unroll
      for (int j2 = 0; j2 < 8; ++j2) wv[j2] = bl[(8 * g + j2) * 16 + ll];
      uint32_t ov[4];
#pragma unroll
      for (int k = 0; k < 4; ++k) {
        uint32_t v = 0;
#pragma unroll
        for (int tt = 0; tt < 4; ++tt) {
          int t = k * 4 + tt;
          uint32_t by = 0;
#pragma unroll
          for (int j2 = 0; j2 < 8; ++j2) by |= ((wv[j2] >> t) & 1u) << j2;
          v |= by << (8 * tt);
        }
        ov[k] = v;
      }
      *(uint4*)((u8*)outp + ((size_t)(b * 128 + lb + ll) * GBo + ct * 8 + g) * 16) =
          make_uint4(ov[0], ov[1], ov[2], ov[3]);
    }
  } else {
    if (tid < 128) {  // 64 co x 2 halves of 8 l (16B each)
      int col = tid >> 1, hf = tid & 1;
      uint4 v = *(const uint4*)(bl + col * 16 + hf * 8);
      *(uint4*)((u16*)outp + ((size_t)b * COUT + ct * 64 + col) * 128 + lb + hf * 8) = v;
    }
  }
}

// ---------------------------------------------------------------------------
// head: conv4 (64->2) + LIF4; fc1 (256->100) split across 2 f-halves (200
// active threads, LDS partial reduce) + LIF5; fc2 accumulated (popcount).
// ---------------------------------------------------------------------------
__global__ __launch_bounds__(256) void head_kernel(
    const u16* __restrict__ s3bits, const float* __restrict__ W4,
    const float* __restrict__ b4, const float* __restrict__ fw1T,
    const float* __restrict__ fb1, const float* __restrict__ fw2T,
    const float* __restrict__ fb2, float* __restrict__ out) {
  __shared__ u16 s3l[64][130];
  __shared__ float W4l[384];
  __shared__ u16 flat4[256];
  __shared__ u16 s5b[100];
  int b = blockIdx.x, tid = threadIdx.x;

  for (int i = tid; i < 64 * 130; i += 256) {
    int ci = i / 130, idx = i % 130, lg = idx - 1;
    s3l[ci][idx] = (lg >= 0 && lg < 128) ? s3bits[((size_t)b * 64 + ci) * 128 + lg] : (u16)0;
  }
  for (int i = tid; i < 384; i += 256) W4l[i] = W4[i];
  __syncthreads();

  {
    int co = tid >> 7, l = tid & 127;
    float acc4[16];
#pragma unroll
    for (int t = 0; t < 16; ++t) acc4[t] = 0.f;
    for (int ci = 0; ci < 64; ++ci) {
#pragma unroll
      for (int k = 0; k < 3; ++k) {
        float wv = W4l[(co * 64 + ci) * 3 + k];
        uint32_t msk = s3l[ci][l + k];
#pragma unroll
        for (int t = 0; t < 16; ++t)
          acc4[t] = fmaf(wv, (float)((msk >> t) & 1u), acc4[t]);
      }
    }
    float bc = b4[co];
    float m = 0.f, sp = 0.f;
    uint32_t bits = 0;
#pragma unroll
    for (int t = 0; t < 16; ++t) {
      m = BETA * m + (acc4[t] + bc) - sp;
      bool s = m > 1.0f;
      bits |= ((uint32_t)s) << t;
      sp = s ? 1.0f : 0.0f;
    }
    flat4[tid] = (u16)bits;
  }
  __syncthreads();

  // fc1 split: threads 0..199 each sum one f-half for one neuron
  float* part5 = (float*)&s3l[0][0];  // s3l dead; 100*16*4 = 6400 B
  float acc5[16];
#pragma unroll
  for (int t = 0; t < 16; ++t) acc5[t] = 0.f;
  int n5 = tid % 100, h5 = tid / 100;
  if (tid < 200) {
    const float* wp = fw1T + (h5 * 128) * 100 + n5;
    for (int f = 0; f < 128; ++f) {
      float wv = wp[f * 100];
      uint32_t msk = flat4[h5 * 128 + f];
#pragma unroll
      for (int t = 0; t < 16; ++t)
        acc5[t] = fmaf(wv, (float)((msk >> t) & 1u), acc5[t]);
    }
    if (h5 == 1) {
#pragma unroll
      for (int t = 0; t < 16; ++t) part5[n5 * 16 + t] = acc5[t];
    }
  }
  __syncthreads();
  if (tid < 100) {
    float bc = fb1[tid];
    float m = 0.f, sp = 0.f;
    uint32_t bits = 0;
#pragma unroll
    for (int t = 0; t < 16; ++t) {
      float cur = acc5[t] + part5[tid * 16 + t] + bc;
      m = BETA * m + cur - sp;
      bool s = m > 1.0f;
      bits |= ((uint32_t)s) << t;
      sp = s ? 1.0f : 0.0f;
    }
    s5b[tid] = (u16)bits;
  }
  __syncthreads();

  if (tid < 40) {
    float a = 0.f;
    for (int i = 0; i < 100; ++i) {
      float wv = fw2T[i * 40 + tid];
      a = fmaf(wv, (float)__popc((uint32_t)s5b[i]), a);
    }
    out[b * 40 + tid] = a * 0.0625f + fb2[tid];
  }
}

// ---------------------------------------------------------------------------
extern "C" void kernel_launch(void* const* d_in, const int* in_sizes, int n_in,
                              void* d_out, int out_size, void* d_ws, size_t ws_size,
                              hipStream_t stream) {
  const float* x   = (const float*)d_in[0];
  const float* W1  = (const float*)d_in[1];
  const float* b1  = (const float*)d_in[2];
  const float* W2  = (const float*)d_in[3];
  const float* b2  = (const float*)d_in[4];
  const float* W3  = (const float*)d_in[5];
  const float* b3  = (const float*)d_in[6];
  const float* W4  = (const float*)d_in[7];
  const float* b4  = (const float*)d_in[8];
  const float* fw1 = (const float*)d_in[9];
  const float* fb1 = (const float*)d_in[10];
  const float* fw2 = (const float*)d_in[11];
  const float* fb2 = (const float*)d_in[12];
  float* out = (float*)d_out;

  char* ws = (char*)d_ws;
  i8*    A2c  = (i8*)(ws);                        // 294912 B [part][cp][ct][tap][co64][ci64]
  i8*    A3c  = (i8*)(ws + 294912);               //  73728 B
  float* fw1T = (float*)(ws + 368640);            // 102400 B
  float* fw2T = (float*)(ws + 471040);            //  16000 B (pad to 487424)
  u8*    SBT2 = (u8*)(ws + 487424);               // 134217728 B [b][l][32][16]
  u8*    SBT3 = (u8*)(ws + 487424 + 134217728);   //  67108864 B [b][l][16][16]
  u16*   s3b  = (u16*)(ws + 487424 + 134217728 + 67108864);  // 33554432 B u16 [b][co][l]
  // total: 235,368,448 B

  prep_kernel<<<dim3(596), dim3(256), 0, stream>>>(W2, W3, fw1, fw2, A2c, A3c, fw1T, fw2T);
  conv1_lif_kernel<<<dim3(2048, 32), dim3(256), 0, stream>>>(x, W1, b1, SBT2);
  conv_mfma_kernel<256, 128, true><<<dim3(2048, 8, 2), dim3(256), 0, stream>>>(SBT2, A2c, b2, SBT3);
  conv_mfma_kernel<128, 64, false><<<dim3(2048, 8, 1), dim3(256), 0, stream>>>(SBT3, A3c, b3, s3b);
  head_kernel<<<dim3(2048), dim3(256), 0, stream>>>(s3b, W4, b4, fw1T, fb1, fw2T, fb2, out);
}